// Round 4
// baseline (162833.923 us; speedup 1.0000x reference)
//
#include <hip/hip_runtime.h>

#define BB 256
#define TT 2048
#define II 64
#define HH 256
#define OO 64
#define FF 16

typedef _Float16 h8 __attribute__((ext_vector_type(8)));

__device__ __forceinline__ float fast_tanh(float z) {
  // tanh(z) = 1 - 2/(1+exp(2z)); exp(2z) = exp2(z*2*log2(e)).
  float e = __builtin_amdgcn_exp2f(z * 2.885390081777927f);
  return 1.0f - 2.0f * __builtin_amdgcn_rcpf(e + 1.0f);
}

// One block per batch row b; thread j owns output row j of BOTH layers fully.
// 256 threads = 4 waves, 1 wave/SIMD. Row-j weights register-resident as
// packed fp16 (104 h8 = 416 VGPRs). h-state double-buffered in LDS fp16;
// dot math is (float)f16*(float)f16 accumulated f32 (v_fma_mix_f32).
// OUTPUT IS F32 (reference returns jnp.float32; "bf16" in the harness label
// is a hard-coded format string, not the buffer dtype).
__global__ __launch_bounds__(256, 1)
void rnn_fused(const float* __restrict__ x, const float* __restrict__ hidden,
               const float* __restrict__ Wih0, const float* __restrict__ Whh0,
               const float* __restrict__ bih0, const float* __restrict__ bhh0,
               const float* __restrict__ Wih1, const float* __restrict__ Whh1,
               const float* __restrict__ bih1, const float* __restrict__ bhh1,
               const float* __restrict__ fcW, const float* __restrict__ fcb,
               float* __restrict__ out)
{
  const int j = threadIdx.x;   // owned output row
  const int b = blockIdx.x;    // batch row

  __shared__ __align__(16) _Float16 xs[2][II];
  __shared__ __align__(16) _Float16 h0s[2][HH];
  __shared__ __align__(16) _Float16 h1s[2][HH];
  __shared__ __align__(16) _Float16 tail[FF][HH];

  // ---- one-time: row-j weights -> registers, packed fp16
  h8 wih0[II / 8], whh0[HH / 8], wih1[HH / 8], whh1[HH / 8];
#pragma unroll
  for (int c = 0; c < II / 8; ++c)
#pragma unroll
    for (int e = 0; e < 8; ++e) wih0[c][e] = (_Float16)Wih0[j * II + 8 * c + e];
#pragma unroll
  for (int c = 0; c < HH / 8; ++c)
#pragma unroll
    for (int e = 0; e < 8; ++e) whh0[c][e] = (_Float16)Whh0[j * HH + 8 * c + e];
#pragma unroll
  for (int c = 0; c < HH / 8; ++c)
#pragma unroll
    for (int e = 0; e < 8; ++e) wih1[c][e] = (_Float16)Wih1[j * HH + 8 * c + e];
#pragma unroll
  for (int c = 0; c < HH / 8; ++c)
#pragma unroll
    for (int e = 0; e < 8; ++e) whh1[c][e] = (_Float16)Whh1[j * HH + 8 * c + e];

  const float bias0 = bih0[j] + bhh0[j];
  const float bias1 = bih1[j] + bhh1[j];

  // initial state (t=0 reads buffer 0)
  h0s[0][j] = (_Float16)hidden[b * HH + j];
  h1s[0][j] = (_Float16)hidden[BB * HH + b * HH + j];
  const float* xrow = x + (size_t)b * TT * II;
  if (j < II) xs[0][j] = (_Float16)xrow[j];
  __syncthreads();

  float h0keep = 0.f, h1keep = 0.f;

  for (int t = 0; t < TT; ++t) {
    const int cur = t & 1, nxt = cur ^ 1;

    // prefetch x[t+1] early (global latency hidden behind layer-0 dot)
    float xn = 0.f;
    if (j < II) {
      int tn = (t + 1 < TT) ? (t + 1) : t;
      xn = xrow[(size_t)tn * II + j];
    }

    // ---- layer 0: pre = bias0 + x[t]·Wih0[j,:] + h0·Whh0[j,:] ----
    float a0 = 0.f, a1 = 0.f, a2 = 0.f, a3 = 0.f;
    {
      const h8* xp = (const h8*)xs[cur];
#pragma unroll
      for (int c = 0; c < II / 8; ++c) {
        h8 v = xp[c], wv = wih0[c];
        float s = 0.f;
#pragma unroll
        for (int e = 0; e < 8; ++e) s += (float)v[e] * (float)wv[e];
        if ((c & 3) == 0) a0 += s; else if ((c & 3) == 1) a1 += s;
        else if ((c & 3) == 2) a2 += s; else a3 += s;
      }
      const h8* hp = (const h8*)h0s[cur];
#pragma unroll
      for (int c = 0; c < HH / 8; ++c) {
        h8 v = hp[c], wv = whh0[c];
        float s = 0.f;
#pragma unroll
        for (int e = 0; e < 8; ++e) s += (float)v[e] * (float)wv[e];
        if ((c & 3) == 0) a0 += s; else if ((c & 3) == 1) a1 += s;
        else if ((c & 3) == 2) a2 += s; else a3 += s;
      }
    }
    const float h0new = fast_tanh(((a0 + a1) + (a2 + a3)) + bias0);
    h0s[nxt][j] = (_Float16)h0new;
    if (j < II) xs[nxt][j] = (_Float16)xn;
    __syncthreads();   // h0s[nxt] ready for layer 1

    // ---- layer 1: pre = bias1 + h0new·Wih1[j,:] + h1·Whh1[j,:] ----
    float c0 = 0.f, c1 = 0.f, c2 = 0.f, c3 = 0.f;
    {
      const h8* gp = (const h8*)h0s[nxt];
      const h8* qp = (const h8*)h1s[cur];
#pragma unroll
      for (int c = 0; c < HH / 8; ++c) {
        h8 v = gp[c], wv = wih1[c];
        float s = 0.f;
#pragma unroll
        for (int e = 0; e < 8; ++e) s += (float)v[e] * (float)wv[e];
        h8 u = qp[c], wu = whh1[c];
#pragma unroll
        for (int e = 0; e < 8; ++e) s += (float)u[e] * (float)wu[e];
        if ((c & 3) == 0) c0 += s; else if ((c & 3) == 1) c1 += s;
        else if ((c & 3) == 2) c2 += s; else c3 += s;
      }
    }
    const float h1new = fast_tanh(((c0 + c1) + (c2 + c3)) + bias1);
    h1s[nxt][j] = (_Float16)h1new;
    if (t >= TT - FF) tail[t - (TT - FF)][j] = (_Float16)h1new;
    if (t == TT - 1) { h0keep = h0new; h1keep = h1new; }
    __syncthreads();   // h1s[nxt], xs[nxt], tail row ready
  }

  // ---- output 1: new_hidden [2,B,H] (f32) at flat offset B*F*O ----
  out[BB * FF * OO + b * HH + j] = h0keep;
  out[BB * FF * OO + BB * HH + b * HH + j] = h1keep;

  // ---- output 0: out[b,f,o] = tail[f]·fcW[o,:] + fcb[o]  ([B,F,O], f32) ----
  const int o = j & 63;
  const int fg = j >> 6;   // covers f = 4*fg .. 4*fg+3
  float acc[4] = {0.f, 0.f, 0.f, 0.f};
  const float* wrow = fcW + o * HH;
  for (int c = 0; c < HH / 8; ++c) {
    float wv[8];
#pragma unroll
    for (int k = 0; k < 8; ++k) wv[k] = wrow[8 * c + k];
#pragma unroll
    for (int ff = 0; ff < 4; ++ff) {
      h8 v = *(const h8*)(&tail[4 * fg + ff][8 * c]);
#pragma unroll
      for (int e = 0; e < 8; ++e) acc[ff] += (float)v[e] * wv[e];
    }
  }
  const float bo = fcb[o];
#pragma unroll
  for (int ff = 0; ff < 4; ++ff)
    out[(b * FF + 4 * fg + ff) * OO + o] = acc[ff] + bo;
}

extern "C" void kernel_launch(void* const* d_in, const int* in_sizes, int n_in,
                              void* d_out, int out_size, void* d_ws, size_t ws_size,
                              hipStream_t stream) {
  (void)in_sizes; (void)n_in; (void)d_ws; (void)ws_size; (void)out_size;
  rnn_fused<<<dim3(BB), dim3(256), 0, stream>>>(
      (const float*)d_in[0],  (const float*)d_in[1],
      (const float*)d_in[2],  (const float*)d_in[3],
      (const float*)d_in[4],  (const float*)d_in[5],
      (const float*)d_in[6],  (const float*)d_in[7],
      (const float*)d_in[8],  (const float*)d_in[9],
      (const float*)d_in[10], (const float*)d_in[11],
      (float*)d_out);
}

// Round 5
// 3604.338 us; speedup vs baseline: 45.1772x; 45.1772x over previous
//
#include <hip/hip_runtime.h>

#define BB 256
#define TT 2048
#define II 64
#define HH 256
#define OO 64
#define FF 16

typedef _Float16 h2 __attribute__((ext_vector_type(2)));
typedef _Float16 h8 __attribute__((ext_vector_type(8)));

__device__ __forceinline__ float fdot2f(h2 a, h2 b, float c) {
#if __has_builtin(__builtin_amdgcn_fdot2)
  return __builtin_amdgcn_fdot2(a, b, c, false);  // v_dot2_f32_f16: 2 MAC, f32 acc
#else
  return c + (float)a[0] * (float)b[0] + (float)a[1] * (float)b[1];
#endif
}

__device__ __forceinline__ float fast_tanh(float z) {
  float e = __builtin_amdgcn_exp2f(z * 2.885390081777927f);
  return 1.0f - 2.0f * __builtin_amdgcn_rcpf(e + 1.0f);
}

__device__ __forceinline__ h2 hpair(h8 v, int q) {
  h2 p; p[0] = v[2 * q]; p[1] = v[2 * q + 1]; return p;
}
__device__ __forceinline__ h2 pk2(const float* p) {
  h2 r; r[0] = (_Float16)p[0]; r[1] = (_Float16)p[1]; return r;
}

// One block per batch row. 512 threads = 8 waves (2/SIMD). Thread (j, half):
// j = tid&255 owns output row j; half = tid>>8 owns K-half of the dot.
// KEY LESSON from R4 counters: arch VGPR cap is 256/wave — 416 weight VGPRs
// spilled to scratch (133 GB HBM refetch, VALUBusy 2.9%). At 2-way K-split,
// weights/thread = 208 VGPRs -> fits under the cap, no spill.
// Waves 0-3 = half 0, waves 4-7 = half 1 (wave-uniform branches).
// 3 barriers/step (hazard audit in comments). All wave LDS reads of x/h are
// same-address broadcasts (conflict-free); partial writes are stride-1.
__global__ __launch_bounds__(512, 2)
void rnn_fused(const float* __restrict__ x, const float* __restrict__ hidden,
               const float* __restrict__ Wih0, const float* __restrict__ Whh0,
               const float* __restrict__ bih0, const float* __restrict__ bhh0,
               const float* __restrict__ Wih1, const float* __restrict__ Whh1,
               const float* __restrict__ bih1, const float* __restrict__ bhh1,
               const float* __restrict__ fcW, const float* __restrict__ fcb,
               float* __restrict__ out)
{
  const int tid = threadIdx.x;
  const int b = blockIdx.x;
  const int j = tid & 255;
  const int half = tid >> 8;

  __shared__ __align__(16) _Float16 xs[II];
  __shared__ __align__(16) _Float16 h0s[HH];
  __shared__ __align__(16) _Float16 h1s[HH];
  __shared__ float part0[2][HH];
  __shared__ float part1[2][HH];
  __shared__ __align__(16) _Float16 tail[FF][HH];

  // ---- one-time: this thread's K-half of row-j weights -> 208 VGPRs fp16
  h2 l0x[16], l0h[64], l1g[64], l1h[64];
  {
    const float* p0 = Wih0 + j * II + 32 * half;
#pragma unroll
    for (int c = 0; c < 16; ++c) l0x[c] = pk2(p0 + 2 * c);
    const float* p1 = Whh0 + j * HH + 128 * half;
#pragma unroll
    for (int c = 0; c < 64; ++c) l0h[c] = pk2(p1 + 2 * c);
    const float* p2 = Wih1 + j * HH + 128 * half;
#pragma unroll
    for (int c = 0; c < 64; ++c) l1g[c] = pk2(p2 + 2 * c);
    const float* p3 = Whh1 + j * HH + 128 * half;
#pragma unroll
    for (int c = 0; c < 64; ++c) l1h[c] = pk2(p3 + 2 * c);
  }

  const float bias0 = bih0[j] + bhh0[j];
  const float bias1 = bih1[j] + bhh1[j];

  if (half == 0) {
    h0s[j] = (_Float16)hidden[b * HH + j];
    h1s[j] = (_Float16)hidden[BB * HH + b * HH + j];
  }
  const float* xrow = x + (size_t)b * TT * II;
  if (tid < II) xs[tid] = (_Float16)xrow[tid];
  float h0keep = 0.f, h1keep = 0.f;
  __syncthreads();

  for (int t = 0; t < TT; ++t) {
    // prefetch x[t+1] (global latency hidden behind P1 math)
    float xn = 0.f;
    if (tid < II) {
      int tn = (t + 1 < TT) ? (t + 1) : t;
      xn = xrow[(size_t)tn * II + tid];
    }

    // ---- P1: layer-0 partial dot over this K-half (16 + 64 fdot2) ----
    float a0 = 0.f, a1 = 0.f;
    {
      const h8* xp = (const h8*)&xs[32 * half];
#pragma unroll
      for (int c = 0; c < 4; ++c) {
        h8 v = xp[c];
        a0 = fdot2f(hpair(v, 0), l0x[4 * c + 0], a0);
        a1 = fdot2f(hpair(v, 1), l0x[4 * c + 1], a1);
        a0 = fdot2f(hpair(v, 2), l0x[4 * c + 2], a0);
        a1 = fdot2f(hpair(v, 3), l0x[4 * c + 3], a1);
      }
      const h8* hp = (const h8*)&h0s[128 * half];
#pragma unroll
      for (int c = 0; c < 16; ++c) {
        h8 v = hp[c];
        a0 = fdot2f(hpair(v, 0), l0h[4 * c + 0], a0);
        a1 = fdot2f(hpair(v, 1), l0h[4 * c + 1], a1);
        a0 = fdot2f(hpair(v, 2), l0h[4 * c + 2], a0);
        a1 = fdot2f(hpair(v, 3), l0h[4 * c + 3], a1);
      }
    }
    part0[half][j] = a0 + a1;
    __syncthreads();  // B1: part0 ready; also orders P1 reads of xs/h0s before P2 writes

    // ---- P2: reduce + tanh (half 0 only: waves 0-3); x store ----
    if (half == 0) {
      float h0new = fast_tanh(part0[0][j] + part0[1][j] + bias0);
      h0s[j] = (_Float16)h0new;
      if (t == TT - 1) h0keep = h0new;
    }
    if (tid < II) xs[tid] = (_Float16)xn;
    __syncthreads();  // B2: h0s/xs writes visible before P3 reads h0s

    // ---- P3: layer-1 partial dot (64 + 64 fdot2) ----
    float c0 = 0.f, c1 = 0.f;
    {
      const h8* gp = (const h8*)&h0s[128 * half];
      const h8* qp = (const h8*)&h1s[128 * half];
#pragma unroll
      for (int c = 0; c < 16; ++c) {
        h8 v = gp[c];
        c0 = fdot2f(hpair(v, 0), l1g[4 * c + 0], c0);
        c1 = fdot2f(hpair(v, 1), l1g[4 * c + 1], c1);
        c0 = fdot2f(hpair(v, 2), l1g[4 * c + 2], c0);
        c1 = fdot2f(hpair(v, 3), l1g[4 * c + 3], c1);
        h8 u = qp[c];
        c0 = fdot2f(hpair(u, 0), l1h[4 * c + 0], c0);
        c1 = fdot2f(hpair(u, 1), l1h[4 * c + 1], c1);
        c0 = fdot2f(hpair(u, 2), l1h[4 * c + 2], c0);
        c1 = fdot2f(hpair(u, 3), l1h[4 * c + 3], c1);
      }
    }
    part1[half][j] = c0 + c1;
    __syncthreads();  // B3: part1 ready; orders P3 reads of h1s before P4 write

    // ---- P4: reduce + tanh + h1 commit (half 0 only). NO barrier needed:
    // h1s written here is next read in t+1 P3 (B1,B2 of t+1 order it);
    // part1 next written in t+1 P3, after B1/B2; part0 next written in
    // t+1 P1, but its last read (this P2) precedes B2. All hazards covered.
    if (half == 0) {
      float h1new = fast_tanh(part1[0][j] + part1[1][j] + bias1);
      h1s[j] = (_Float16)h1new;
      if (t >= TT - FF) tail[t - (TT - FF)][j] = (_Float16)h1new;
      if (t == TT - 1) h1keep = h1new;
    }
  }
  __syncthreads();  // tail complete before FC

  // ---- output 1: new_hidden [2,B,H] f32 at flat offset B*F*O ----
  if (half == 0) {
    out[BB * FF * OO + b * HH + j] = h0keep;
    out[BB * FF * OO + BB * HH + b * HH + j] = h1keep;
  }

  // ---- output 0: out[b,f,o] = tail[f]·fcW[o,:] + fcb[o]  ([B,F,O] f32) ----
  // 512 threads cover 64 o × 8 f-groups × 2 f each.
  const int o = tid & 63;
  const int fg = tid >> 6;  // 0..7 -> f = 2*fg, 2*fg+1
  float acc0 = 0.f, acc1 = 0.f;
  const float* wrow = fcW + o * HH;
  for (int c = 0; c < HH / 8; ++c) {
    float wv[8];
#pragma unroll
    for (int k = 0; k < 8; ++k) wv[k] = wrow[8 * c + k];
    h8 v0 = *(const h8*)&tail[2 * fg][8 * c];
    h8 v1 = *(const h8*)&tail[2 * fg + 1][8 * c];
#pragma unroll
    for (int e = 0; e < 8; ++e) {
      acc0 += (float)v0[e] * wv[e];
      acc1 += (float)v1[e] * wv[e];
    }
  }
  const float bo = fcb[o];
  out[(b * FF + 2 * fg) * OO + o] = acc0 + bo;
  out[(b * FF + 2 * fg + 1) * OO + o] = acc1 + bo;
}

extern "C" void kernel_launch(void* const* d_in, const int* in_sizes, int n_in,
                              void* d_out, int out_size, void* d_ws, size_t ws_size,
                              hipStream_t stream) {
  (void)in_sizes; (void)n_in; (void)d_ws; (void)ws_size; (void)out_size;
  rnn_fused<<<dim3(BB), dim3(512), 0, stream>>>(
      (const float*)d_in[0],  (const float*)d_in[1],
      (const float*)d_in[2],  (const float*)d_in[3],
      (const float*)d_in[4],  (const float*)d_in[5],
      (const float*)d_in[6],  (const float*)d_in[7],
      (const float*)d_in[8],  (const float*)d_in[9],
      (const float*)d_in[10], (const float*)d_in[11],
      (float*)d_out);
}

// Round 6
// 3581.483 us; speedup vs baseline: 45.4655x; 1.0064x over previous
//
#include <hip/hip_runtime.h>

#define BB 256
#define TT 2048
#define II 64
#define HH 256
#define OO 64
#define FF 16

typedef _Float16 h2 __attribute__((ext_vector_type(2)));
typedef _Float16 h8 __attribute__((ext_vector_type(8)));

__device__ __forceinline__ float fdot2f(h2 a, h2 b, float c) {
#if __has_builtin(__builtin_amdgcn_fdot2)
  return __builtin_amdgcn_fdot2(a, b, c, false);  // v_dot2_f32_f16
#else
  return c + (float)a[0] * (float)b[0] + (float)a[1] * (float)b[1];
#endif
}

__device__ __forceinline__ float fast_tanh(float z) {
  float e = __builtin_amdgcn_exp2f(z * 2.885390081777927f);
  return 1.0f - 2.0f * __builtin_amdgcn_rcpf(e + 1.0f);
}

__device__ __forceinline__ h2 hpair(h8 v, int q) {
  h2 p; p[0] = v[2 * q]; p[1] = v[2 * q + 1]; return p;
}
__device__ __forceinline__ h2 i2h(int w) {
  union { int i; h2 h; } u; u.i = w; return u.h;
}
__device__ __forceinline__ int pk2i(const float* p) {
  union { h2 h; int i; } u; u.h[0] = (_Float16)p[0]; u.h[1] = (_Float16)p[1];
  return u.i;
}

// One block per batch row. 512 threads = 8 waves (2/SIMD). Thread (j, half):
// j = tid&255 owns output row j; half = tid>>8 owns a K-half of each dot.
//
// R4 lesson: >256 VGPR/thread spills to scratch (133 GB HBM, 2.9% VALU).
// R5 lesson: VGPR_Count=128 — the allocator REMATERIALIZED the weight loads
// inside the t-loop, re-reading 416 B/thread/step from L2 at ~30 TB/s (the
// measured L2 ceiling) -> L2-BW-bound, VALUBusy 45%. Fix: pin each packed
// weight with an opaque asm pass-through so remat is impossible. Budget:
// 208 weight + ~35 working = 243 < 256 cap from __launch_bounds__(512,2);
// 8 waves x 243 x 64 x 4B = 498 KB <= 512 KB CU register file.
__global__ __launch_bounds__(512, 2)
void rnn_fused(const float* __restrict__ x, const float* __restrict__ hidden,
               const float* __restrict__ Wih0, const float* __restrict__ Whh0,
               const float* __restrict__ bih0, const float* __restrict__ bhh0,
               const float* __restrict__ Wih1, const float* __restrict__ Whh1,
               const float* __restrict__ bih1, const float* __restrict__ bhh1,
               const float* __restrict__ fcW, const float* __restrict__ fcb,
               float* __restrict__ out)
{
  const int tid = threadIdx.x;
  const int b = blockIdx.x;
  const int j = tid & 255;
  const int half = tid >> 8;

  __shared__ __align__(16) _Float16 xs[II];
  __shared__ __align__(16) _Float16 h0s[HH];
  __shared__ __align__(16) _Float16 h1s[HH];
  __shared__ float part0[2][HH];
  __shared__ float part1[2][HH];
  __shared__ __align__(16) _Float16 tail[FF][HH];

  // ---- one-time: this thread's K-half of row-j weights -> 208 pinned VGPRs
  int l0x[16], l0h[64], l1g[64], l1h[64];
  {
    const float* p0 = Wih0 + j * II + 32 * half;
#pragma unroll
    for (int c = 0; c < 16; ++c) l0x[c] = pk2i(p0 + 2 * c);
    const float* p1 = Whh0 + j * HH + 128 * half;
#pragma unroll
    for (int c = 0; c < 64; ++c) l0h[c] = pk2i(p1 + 2 * c);
    const float* p2 = Wih1 + j * HH + 128 * half;
#pragma unroll
    for (int c = 0; c < 64; ++c) l1g[c] = pk2i(p2 + 2 * c);
    const float* p3 = Whh1 + j * HH + 128 * half;
#pragma unroll
    for (int c = 0; c < 64; ++c) l1h[c] = pk2i(p3 + 2 * c);
  }
  // Opaque pass-through: compiler can no longer remat these from memory.
#pragma unroll
  for (int c = 0; c < 16; ++c) asm volatile("" : "+v"(l0x[c]));
#pragma unroll
  for (int c = 0; c < 64; ++c) asm volatile("" : "+v"(l0h[c]));
#pragma unroll
  for (int c = 0; c < 64; ++c) asm volatile("" : "+v"(l1g[c]));
#pragma unroll
  for (int c = 0; c < 64; ++c) asm volatile("" : "+v"(l1h[c]));

  const float bias0 = bih0[j] + bhh0[j];
  const float bias1 = bih1[j] + bhh1[j];

  if (half == 0) {
    h0s[j] = (_Float16)hidden[b * HH + j];
    h1s[j] = (_Float16)hidden[BB * HH + b * HH + j];
  }
  const float* xrow = x + (size_t)b * TT * II;
  if (tid < II) xs[tid] = (_Float16)xrow[tid];
  float h0keep = 0.f, h1keep = 0.f;
  __syncthreads();

  for (int t = 0; t < TT; ++t) {
    // prefetch x[t+1] (global latency hidden behind P1 math)
    float xn = 0.f;
    if (tid < II) {
      int tn = (t + 1 < TT) ? (t + 1) : t;
      xn = xrow[(size_t)tn * II + tid];
    }

    // ---- P1: layer-0 partial dot over this K-half (16 + 64 fdot2) ----
    float a0 = 0.f, a1 = 0.f;
    {
      const h8* xp = (const h8*)&xs[32 * half];
#pragma unroll
      for (int c = 0; c < 4; ++c) {
        h8 v = xp[c];
        a0 = fdot2f(hpair(v, 0), i2h(l0x[4 * c + 0]), a0);
        a1 = fdot2f(hpair(v, 1), i2h(l0x[4 * c + 1]), a1);
        a0 = fdot2f(hpair(v, 2), i2h(l0x[4 * c + 2]), a0);
        a1 = fdot2f(hpair(v, 3), i2h(l0x[4 * c + 3]), a1);
      }
      const h8* hp = (const h8*)&h0s[128 * half];
#pragma unroll
      for (int c = 0; c < 16; ++c) {
        h8 v = hp[c];
        a0 = fdot2f(hpair(v, 0), i2h(l0h[4 * c + 0]), a0);
        a1 = fdot2f(hpair(v, 1), i2h(l0h[4 * c + 1]), a1);
        a0 = fdot2f(hpair(v, 2), i2h(l0h[4 * c + 2]), a0);
        a1 = fdot2f(hpair(v, 3), i2h(l0h[4 * c + 3]), a1);
      }
    }
    part0[half][j] = a0 + a1;
    __syncthreads();  // B1: part0 ready; orders P1 reads of xs/h0s before P2 writes

    // ---- P2: reduce + tanh (half 0: waves 0-3); x store ----
    if (half == 0) {
      float h0new = fast_tanh(part0[0][j] + part0[1][j] + bias0);
      h0s[j] = (_Float16)h0new;
      if (t == TT - 1) h0keep = h0new;
    }
    if (tid < II) xs[tid] = (_Float16)xn;
    __syncthreads();  // B2: h0s/xs writes visible before P3 reads

    // ---- P3: layer-1 partial dot (64 + 64 fdot2) ----
    float c0 = 0.f, c1 = 0.f;
    {
      const h8* gp = (const h8*)&h0s[128 * half];
      const h8* qp = (const h8*)&h1s[128 * half];
#pragma unroll
      for (int c = 0; c < 16; ++c) {
        h8 v = gp[c];
        c0 = fdot2f(hpair(v, 0), i2h(l1g[4 * c + 0]), c0);
        c1 = fdot2f(hpair(v, 1), i2h(l1g[4 * c + 1]), c1);
        c0 = fdot2f(hpair(v, 2), i2h(l1g[4 * c + 2]), c0);
        c1 = fdot2f(hpair(v, 3), i2h(l1g[4 * c + 3]), c1);
        h8 u = qp[c];
        c0 = fdot2f(hpair(u, 0), i2h(l1h[4 * c + 0]), c0);
        c1 = fdot2f(hpair(u, 1), i2h(l1h[4 * c + 1]), c1);
        c0 = fdot2f(hpair(u, 2), i2h(l1h[4 * c + 2]), c0);
        c1 = fdot2f(hpair(u, 3), i2h(l1h[4 * c + 3]), c1);
      }
    }
    part1[half][j] = c0 + c1;
    __syncthreads();  // B3: part1 ready; orders P3 reads of h1s before P4 write

    // ---- P4: reduce + tanh + h1 commit (half 0). No barrier needed here:
    // next access to h1s/part1/part0 is ordered by B1/B2 of step t+1.
    if (half == 0) {
      float h1new = fast_tanh(part1[0][j] + part1[1][j] + bias1);
      h1s[j] = (_Float16)h1new;
      if (t >= TT - FF) tail[t - (TT - FF)][j] = (_Float16)h1new;
      if (t == TT - 1) h1keep = h1new;
    }
  }
  __syncthreads();  // tail complete before FC

  // ---- output 1: new_hidden [2,B,H] f32 at flat offset B*F*O ----
  if (half == 0) {
    out[BB * FF * OO + b * HH + j] = h0keep;
    out[BB * FF * OO + BB * HH + b * HH + j] = h1keep;
  }

  // ---- output 0: out[b,f,o] = tail[f]·fcW[o,:] + fcb[o]  ([B,F,O] f32) ----
  const int o = tid & 63;
  const int fg = tid >> 6;  // 0..7 -> f = 2*fg, 2*fg+1
  float acc0 = 0.f, acc1 = 0.f;
  const float* wrow = fcW + o * HH;
  for (int c = 0; c < HH / 8; ++c) {
    float wv[8];
#pragma unroll
    for (int k = 0; k < 8; ++k) wv[k] = wrow[8 * c + k];
    h8 v0 = *(const h8*)&tail[2 * fg][8 * c];
    h8 v1 = *(const h8*)&tail[2 * fg + 1][8 * c];
#pragma unroll
    for (int e = 0; e < 8; ++e) {
      acc0 += (float)v0[e] * wv[e];
      acc1 += (float)v1[e] * wv[e];
    }
  }
  const float bo = fcb[o];
  out[(b * FF + 2 * fg) * OO + o] = acc0 + bo;
  out[(b * FF + 2 * fg + 1) * OO + o] = acc1 + bo;
}

extern "C" void kernel_launch(void* const* d_in, const int* in_sizes, int n_in,
                              void* d_out, int out_size, void* d_ws, size_t ws_size,
                              hipStream_t stream) {
  (void)in_sizes; (void)n_in; (void)d_ws; (void)ws_size; (void)out_size;
  rnn_fused<<<dim3(BB), dim3(512), 0, stream>>>(
      (const float*)d_in[0],  (const float*)d_in[1],
      (const float*)d_in[2],  (const float*)d_in[3],
      (const float*)d_in[4],  (const float*)d_in[5],
      (const float*)d_in[6],  (const float*)d_in[7],
      (const float*)d_in[8],  (const float*)d_in[9],
      (const float*)d_in[10], (const float*)d_in[11],
      (float*)d_out);
}